// Round 8
// baseline (18.275 us; speedup 1.0000x reference)
//
#include <hip/hip_runtime.h>

#define NPROPS   32
#define BUCKCAP  1024    // per-(property,label) LDS capacity; expected ~128
#define NTHREADS 1024
#define MARGIN   1.0f
#define MAGIC    0x5EC7ED5Eu

// Partials published with device-scope atomics (coherent across XCDs).
// Values are replay-invariant (to float-ULP), so a block reading a stale
// partial on replay k>=1 still produces a correct result. First call sees
// garbage flags != MAGIC whp -> only the true last finisher writes out.
struct Ws {
    unsigned long long loss_bits[NPROPS];  // double partial, bit-cast
    unsigned long long pairs[NPROPS];      // npos_p * nneg_p
    unsigned int       flag[NPROPS];       // MAGIC once published
};

__global__ __launch_bounds__(NTHREADS)
void fused_tail_kernel(const float* __restrict__ scores,
                       const int*   __restrict__ labels,
                       const int*   __restrict__ pids,
                       Ws* __restrict__ ws,
                       float* __restrict__ out, int n) {
    const int p   = blockIdx.x;      // property this block owns
    const int tid = threadIdx.x;

    __shared__ float pos_s[BUCKCAP];
    __shared__ float neg_s[BUCKCAP];
    __shared__ int   cnt[2];         // [0]=#neg, [1]=#pos
    __shared__ float wsum[NTHREADS / 64];

    if (tid < 2) cnt[tid] = 0;
    __syncthreads();

    // ---- vectorized scan (2 rounds of 16B loads per array), R5-proven ----
    const int4*   pid4v = (const int4*)pids;
    const int4*   lab4v = (const int4*)labels;
    const float4* sc4v  = (const float4*)scores;
    const int nvec = n >> 2;                     // n % 4 == 0 (8192)
    for (int v = tid; v < nvec; v += NTHREADS) {
        int4   pd = pid4v[v];
        int4   lb = lab4v[v];
        float4 sc = sc4v[v];
        #pragma unroll
        for (int k = 0; k < 4; ++k) {
            if ((&pd.x)[k] == p) {
                const int   lk  = (&lb.x)[k];
                const int   idx = atomicAdd(&cnt[lk], 1);
                const float sk  = (&sc.x)[k];
                if (lk) pos_s[idx] = sk; else neg_s[idx] = sk;
            }
        }
    }
    __syncthreads();

    const int nneg = cnt[0];
    const int npos = cnt[1];

    // ---- pair sweep: 8 threads per positive, j striped by 8 (R5) ----
    float acc = 0.0f;
    const int j0 = tid & 7;
    for (int i = tid >> 3; i < npos; i += NTHREADS / 8) {
        const float a = MARGIN - pos_s[i];
        for (int j = j0; j < nneg; j += 8)
            acc += fmaxf(a + neg_s[j], 0.0f);
    }

    // ---- block reduction ----
    #pragma unroll
    for (int off = 32; off > 0; off >>= 1)
        acc += __shfl_down(acc, off);
    if ((tid & 63) == 0) wsum[tid >> 6] = acc;
    __syncthreads();

    // ---- publish this block's partial (R4-proven machinery) ----
    if (tid == 0) {
        float s = 0.0f;
        #pragma unroll
        for (int w = 0; w < NTHREADS / 64; ++w) s += wsum[w];
        atomicExch(&ws->loss_bits[p],
                   (unsigned long long)__double_as_longlong((double)s));
        atomicExch(&ws->pairs[p],
                   (unsigned long long)npos * (unsigned long long)nneg);
        __threadfence();
        atomicExch(&ws->flag[p], MAGIC);
    }
    __threadfence();   // wave-wide: own publishes complete before tail reads

    // ---- single-shot tail (wave 0 only): if all 32 flags are MAGIC,
    //      this block is (or ties with) the last finisher -> finalize. ----
    if (tid < 64) {
        bool ok = true;
        if (tid < NPROPS && tid != p)
            ok = (atomicAdd(&ws->flag[tid], 0u) == MAGIC);
        if (__all(ok)) {
            __threadfence();
            double             l = 0.0;
            unsigned long long c = 0;
            if (tid < NPROPS) {
                l = __longlong_as_double(
                        (long long)atomicAdd(&ws->loss_bits[tid], 0ull));
                c = atomicAdd(&ws->pairs[tid], 0ull);
            }
            #pragma unroll
            for (int off = 16; off > 0; off >>= 1) {
                l += __shfl_down(l, off);
                c += __shfl_down(c, off);
            }
            if (tid == 0)
                out[0] = (c == 0) ? 0.0f : (float)(l / (double)c);
        }
    }
}

extern "C" void kernel_launch(void* const* d_in, const int* in_sizes, int n_in,
                              void* d_out, int out_size, void* d_ws, size_t ws_size,
                              hipStream_t stream) {
    const float* scores = (const float*)d_in[0];
    const int*   labels = (const int*)d_in[1];
    const int*   pids   = (const int*)d_in[2];
    const int    n      = in_sizes[0];

    fused_tail_kernel<<<NPROPS, NTHREADS, 0, stream>>>(scores, labels, pids,
                                                       (Ws*)d_ws,
                                                       (float*)d_out, n);
}

// Round 9
// 11.899 us; speedup vs baseline: 1.5358x; 1.5358x over previous
//
#include <hip/hip_runtime.h>

#define NPROPS   32
#define BUCKCAP  1024    // per-(property,label) LDS capacity; expected ~128
#define NTHREADS 1024
#define MARGIN   1.0f

// Per-block partials; every block writes its own slot unconditionally every
// call -> no zero-init required, deterministic under graph replay.
struct Ws {
    double    loss[NPROPS];
    long long pairs[NPROPS];
};

// ---------------------------------------------------------------------------
// Kernel 1: one block (1024 thr, 16 waves) per property. Scan all inputs in
// 2 vectorized rounds, bucket this property's pos/neg scores into LDS,
// pair-sweep with an 8-wide j-stripe so all 1024 threads are busy,
// block-reduce, write one partial.
// ---------------------------------------------------------------------------
__global__ __launch_bounds__(NTHREADS)
void fused_kernel(const float* __restrict__ scores,
                  const int*   __restrict__ labels,
                  const int*   __restrict__ pids,
                  Ws* __restrict__ ws, int n) {
    const int p   = blockIdx.x;      // property this block owns
    const int tid = threadIdx.x;

    __shared__ float pos_s[BUCKCAP];
    __shared__ float neg_s[BUCKCAP];
    __shared__ int   cnt[2];         // [0]=#neg, [1]=#pos
    __shared__ float wsum[NTHREADS / 64];

    if (tid < 2) cnt[tid] = 0;
    __syncthreads();

    // ---- vectorized scan (2 rounds of 16B loads per array) ----
    const int4*   pid4v = (const int4*)pids;
    const int4*   lab4v = (const int4*)labels;
    const float4* sc4v  = (const float4*)scores;
    const int nvec = n >> 2;                     // n % 4 == 0 (8192)
    for (int v = tid; v < nvec; v += NTHREADS) {
        int4   pd = pid4v[v];
        int4   lb = lab4v[v];
        float4 sc = sc4v[v];
        #pragma unroll
        for (int k = 0; k < 4; ++k) {
            if ((&pd.x)[k] == p) {
                const int   lk  = (&lb.x)[k];
                const int   idx = atomicAdd(&cnt[lk], 1);
                const float sk  = (&sc.x)[k];
                if (lk) pos_s[idx] = sk; else neg_s[idx] = sk;
            }
        }
    }
    __syncthreads();

    const int nneg = cnt[0];
    const int npos = cnt[1];

    // ---- pair sweep: 8 threads per positive, j striped by 8.
    //      128 positives per outer round -> all 1024 threads active. ----
    float acc = 0.0f;
    const int j0 = tid & 7;
    for (int i = tid >> 3; i < npos; i += NTHREADS / 8) {
        const float a = MARGIN - pos_s[i];
        for (int j = j0; j < nneg; j += 8)
            acc += fmaxf(a + neg_s[j], 0.0f);
    }

    // ---- block reduction ----
    #pragma unroll
    for (int off = 32; off > 0; off >>= 1)
        acc += __shfl_down(acc, off);
    if ((tid & 63) == 0) wsum[tid >> 6] = acc;
    __syncthreads();

    if (tid == 0) {
        float s = 0.0f;
        #pragma unroll
        for (int w = 0; w < NTHREADS / 64; ++w) s += wsum[w];
        ws->loss[p]  = (double)s;
        ws->pairs[p] = (long long)npos * (long long)nneg;
    }
}

// ---------------------------------------------------------------------------
// Kernel 2: one wave reduces the 32 partials and writes the mean.
// ---------------------------------------------------------------------------
__global__ __launch_bounds__(64)
void finalize_kernel(const Ws* __restrict__ ws, float* __restrict__ out) {
    const int lane = threadIdx.x;
    double    l = (lane < NPROPS) ? ws->loss[lane]  : 0.0;
    long long c = (lane < NPROPS) ? ws->pairs[lane] : 0;
    #pragma unroll
    for (int off = 32; off > 0; off >>= 1) {
        l += __shfl_down(l, off);
        c += __shfl_down(c, off);
    }
    if (lane == 0) out[0] = (c == 0) ? 0.0f : (float)(l / (double)c);
}

extern "C" void kernel_launch(void* const* d_in, const int* in_sizes, int n_in,
                              void* d_out, int out_size, void* d_ws, size_t ws_size,
                              hipStream_t stream) {
    const float* scores = (const float*)d_in[0];
    const int*   labels = (const int*)d_in[1];
    const int*   pids   = (const int*)d_in[2];
    const int    n      = in_sizes[0];
    Ws* ws = (Ws*)d_ws;

    fused_kernel<<<NPROPS, NTHREADS, 0, stream>>>(scores, labels, pids, ws, n);
    finalize_kernel<<<1, 64, 0, stream>>>(ws, (float*)d_out);
}